// Round 6
// baseline (6984.920 us; speedup 1.0000x reference)
//
#include <hip/hip_runtime.h>
#include <cstdint>
#include <cstddef>

#define B_MOL 512
#define A_PER 64
#define ED_PER 256
#define N_ATOMS (B_MOL * A_PER)   // 32768
#define N_DIR (B_MOL * ED_PER)    // 131072
#define N_UND (B_MOL * 128)       // 65536
#define HID 256
#define OUT_STRIDE 12289

__device__ __forceinline__ int e_src(int e) {
  return (e < 64) ? e : (e < 128) ? (e - 64)
       : (e < 192) ? ((e - 127) & 63) : ((e - 190) & 63);
}
__device__ __forceinline__ int row2e(int t, int r) { return 64 * t + r + ((r & 64) ? 64 : 0); }

// ---------------------------------------------------------------------------
// fp32 LDS-tiled GEMM, 64x64 tile, BK=16, 256 threads, 4x4/thread.
// AMODE: 0 dense fp32 A [M,lda];
//        2 W_o concat: k<256 -> A(asumf)[row*256+k], k in [256,354) ->
//          A2(f_atoms)[row*98+k-256]; B rows remapped (98+k / k-256);
//        3 VcVv: k<256 -> A(afat), k>=256 -> A2(prev_hid); B transposed:
//          k<256 -> B(W_vc)[n][k], else B2(W_vv)[n][k-256];
//        4 bond-pair gather of fp32 atom_feats (K=512).
// outmode: 0 fp32 dense (ldco,outcol); 2 atom-head strided; 3 bond-head strided.
// ---------------------------------------------------------------------------
template <int AMODE>
__launch_bounds__(256)
__global__ void fgemm(const float* __restrict__ A, const float* __restrict__ A2,
                      const float* __restrict__ B, const float* __restrict__ B2,
                      const float* __restrict__ addend,
                      const float* __restrict__ bias,
                      float* __restrict__ outf,
                      int M, int N, int K, int lda, int ldb, int ldco, int outcol,
                      int relu, int outmode) {
  __shared__ float As[64][17];
  __shared__ float Bs[16][65];
  const int tid = threadIdx.x;
  const int tx = tid & 15, ty = tid >> 4;
  const int tileM = blockIdx.x * 64, tileN = blockIdx.y * 64;
  float acc[4][4] = {};

  const int nkb = (K + 15) >> 4;
  for (int kb = 0; kb < nkb; ++kb) {
    __syncthreads();
    // stage A: 64 rows x 16 k
    {
      int m = tid >> 2, k0 = (tid & 3) * 4;
      int row = tileM + m;
#pragma unroll
      for (int z = 0; z < 4; ++z) {
        int k = kb * 16 + k0 + z;
        float v = 0.f;
        if (k < K) {
          if (AMODE == 0) v = A[(size_t)row * lda + k];
          else if (AMODE == 2) v = (k < 256) ? A[(size_t)row * 256 + k]
                                             : A2[(size_t)row * 98 + (k - 256)];
          else if (AMODE == 3) v = (k < 256) ? A[(size_t)row * 256 + k]
                                             : A2[(size_t)row * 256 + (k - 256)];
          else {  // AMODE 4: bond gather
            int mol = row >> 7, u = row & 127;
            int a0 = (u < 64) ? u : (u - 64);
            int a1v = (u < 64) ? ((u + 1) & 63) : ((u - 62) & 63);
            int atom = (k < 256) ? a0 : a1v;
            v = A[(size_t)(mol * 64 + atom) * 256 + (k & 255)];
          }
        }
        As[m][k0 + z] = v;
      }
    }
    // stage B: 16 k x 64 n
#pragma unroll
    for (int it = 0; it < 4; ++it) {
      int e = it * 256 + tid;
      int kk = e >> 6, n = e & 63;
      int k = kb * 16 + kk, nn = tileN + n;
      float v = 0.f;
      if (k < K && nn < N) {
        if (AMODE == 2) v = (k < 256) ? B[(size_t)(98 + k) * ldb + nn]
                                      : B[(size_t)(k - 256) * ldb + nn];
        else if (AMODE == 3) v = (k < 256) ? B[(size_t)nn * 256 + k]
                                           : B2[(size_t)nn * 256 + (k - 256)];
        else v = B[(size_t)k * ldb + nn];
      }
      Bs[kk][n] = v;
    }
    __syncthreads();
#pragma unroll
    for (int kk = 0; kk < 16; ++kk) {
      float a[4], b[4];
#pragma unroll
      for (int i = 0; i < 4; ++i) a[i] = As[ty * 4 + i][kk];
#pragma unroll
      for (int j = 0; j < 4; ++j) b[j] = Bs[kk][tx * 4 + j];
#pragma unroll
      for (int i = 0; i < 4; ++i)
#pragma unroll
        for (int j = 0; j < 4; ++j) acc[i][j] += a[i] * b[j];
    }
  }

#pragma unroll
  for (int i = 0; i < 4; ++i) {
    size_t row = (size_t)tileM + ty * 4 + i;
#pragma unroll
    for (int j = 0; j < 4; ++j) {
      int col = tileN + tx * 4 + j;
      if (col >= N) continue;
      float v = acc[i][j];
      if (bias) v += bias[col];
      if (addend) v += addend[row * 256 + col];
      if (relu) v = fmaxf(v, 0.f);
      if (outmode == 0) {
        outf[row * ldco + outcol + col] = v;
      } else if (outmode == 2) {
        int mol = (int)(row >> 6), t = (int)(row & 63);
        outf[(size_t)mol * OUT_STRIDE + 4096 + t * 128 + col] = v;
      } else {  // 3
        int mol = (int)(row >> 7), u = (int)(row & 127);
        outf[(size_t)mol * OUT_STRIDE + u * 32 + col] = v;
      }
    }
  }
}

// ---------------------------------------------------------------------------
// Fused DMPNN iteration, ALL fp32, h stored fp32, h0 recomputed inline.
// Block = 128 rev-closed edge rows x full N=256 (sole reader+writer of its
// h rows -> in-place race-free). 1024 thr, 4x8/thread, BK=16.
// Phase 1: acc = fb@W_i (K=111); mid-relu -> h0. Phase 2: acc += m@W_h where
// m = asumf[src(e)] - h[rev(e)]. Epilogue: h = relu(acc).
// ---------------------------------------------------------------------------
__launch_bounds__(1024)
__global__ void msg_f(const float* __restrict__ asumf,
                      float* h,
                      const float* __restrict__ Wh,
                      const float* __restrict__ Wi,
                      const float* __restrict__ fb) {
  __shared__ float As[16][136];
  __shared__ float Bs[16][264];
  const int tid = threadIdx.x;
  const int tx = tid & 31, ty = tid >> 5;
  const int molT = blockIdx.x >> 1, tT = blockIdx.x & 1;
  float acc[4][8] = {};

  // ---- phase 1: h0 = relu(f_bonds @ W_i), K=111 ----
  for (int kb = 0; kb < 7; ++kb) {
    __syncthreads();
#pragma unroll
    for (int it = 0; it < 2; ++it) {
      int e = it * 1024 + tid;
      int kk = e >> 7, r = e & 127;
      int k = kb * 16 + kk;
      int eg = molT * 256 + row2e(tT, r);
      As[kk][r] = (k < 111) ? fb[(size_t)eg * 111 + k] : 0.f;
    }
#pragma unroll
    for (int it = 0; it < 4; ++it) {
      int e = it * 1024 + tid;
      int kk = e >> 8, n = e & 255;
      int k = kb * 16 + kk;
      Bs[kk][n] = (k < 111) ? Wi[(size_t)k * 256 + n] : 0.f;
    }
    __syncthreads();
#pragma unroll
    for (int kk = 0; kk < 16; ++kk) {
      float a[4], b[8];
#pragma unroll
      for (int i = 0; i < 4; ++i) a[i] = As[kk][ty * 4 + i];
#pragma unroll
      for (int j = 0; j < 8; ++j) b[j] = Bs[kk][tx * 8 + j];
#pragma unroll
      for (int i = 0; i < 4; ++i)
#pragma unroll
        for (int j = 0; j < 8; ++j) acc[i][j] += a[i] * b[j];
    }
  }
  // mid-relu: acc now holds h0
#pragma unroll
  for (int i = 0; i < 4; ++i)
#pragma unroll
    for (int j = 0; j < 8; ++j) acc[i][j] = fmaxf(acc[i][j], 0.f);

  // ---- phase 2: acc += m @ W_h ----
  for (int kb = 0; kb < 16; ++kb) {
    __syncthreads();
#pragma unroll
    for (int it = 0; it < 2; ++it) {
      int e = it * 1024 + tid;
      int kk = e >> 7, r = e & 127;
      int eg = row2e(tT, r);
      int s = e_src(eg);
      int rv = (eg < 128) ? (eg + 128) : (eg - 128);
      int k = kb * 16 + kk;
      As[kk][r] = asumf[(size_t)(molT * 64 + s) * 256 + k]
                - h[(size_t)(molT * 256 + rv) * 256 + k];
    }
#pragma unroll
    for (int it = 0; it < 4; ++it) {
      int e = it * 1024 + tid;
      int kk = e >> 8, n = e & 255;
      Bs[kk][n] = Wh[(size_t)(kb * 16 + kk) * 256 + n];
    }
    __syncthreads();
#pragma unroll
    for (int kk = 0; kk < 16; ++kk) {
      float a[4], b[8];
#pragma unroll
      for (int i = 0; i < 4; ++i) a[i] = As[kk][ty * 4 + i];
#pragma unroll
      for (int j = 0; j < 8; ++j) b[j] = Bs[kk][tx * 8 + j];
#pragma unroll
      for (int i = 0; i < 4; ++i)
#pragma unroll
        for (int j = 0; j < 8; ++j) acc[i][j] += a[i] * b[j];
    }
  }

#pragma unroll
  for (int i = 0; i < 4; ++i) {
    int r = ty * 4 + i;
    size_t row = (size_t)molT * 256 + row2e(tT, r);
#pragma unroll
    for (int j = 0; j < 8; ++j) {
      int col = tx * 8 + j;
      h[row * 256 + col] = fmaxf(acc[i][j], 0.f);
    }
  }
}

// a_sum over the 4 incoming directed edges of each atom (fp32 h -> fp32 out)
__global__ __launch_bounds__(256) void asum_f(const float* __restrict__ h,
                                              float* __restrict__ out) {
  int g = blockIdx.x * 256 + threadIdx.x;  // 32768 atoms x 64 chunks of 4
  int atom = g >> 6, cc = (g & 63) << 2;
  int mol = atom >> 6, t = atom & 63;
  const float* hb = h + (size_t)mol * ED_PER * HID;
  int e0 = (t + 63) & 63;
  int e1 = 64 + ((t + 62) & 63);
  int e2 = 128 + t;
  int e3 = 192 + t;
  float4 v0 = *(const float4*)(hb + (size_t)e0 * HID + cc);
  float4 v1 = *(const float4*)(hb + (size_t)e1 * HID + cc);
  float4 v2 = *(const float4*)(hb + (size_t)e2 * HID + cc);
  float4 v3 = *(const float4*)(hb + (size_t)e3 * HID + cc);
  float4 o;
  o.x = v0.x + v1.x + v2.x + v3.x;
  o.y = v0.y + v1.y + v2.y + v3.y;
  o.z = v0.z + v1.z + v2.z + v3.z;
  o.w = v0.w + v1.w + v2.w + v3.w;
  *(float4*)(out + (size_t)atom * HID + cc) = o;
}

// flash attention, fp32 I/O: one wave per (mol, head)
__global__ __launch_bounds__(64) void attn_k(const float* __restrict__ qkv,
                                             float* __restrict__ ctx) {
  __shared__ float kls[64 * 32];
  __shared__ float vls[64 * 32];
  int mol = blockIdx.x >> 3, head = blockIdx.x & 7;
  int lane = threadIdx.x;
  size_t rb = ((size_t)(mol * 64 + lane)) * 768 + head * 32;
#pragma unroll
  for (int c = 0; c < 8; ++c) {
    *(float4*)(kls + lane * 32 + c * 4) = *(const float4*)(qkv + rb + 256 + c * 4);
    *(float4*)(vls + lane * 32 + c * 4) = *(const float4*)(qkv + rb + 512 + c * 4);
  }
  float q[32];
#pragma unroll
  for (int d = 0; d < 32; ++d) q[d] = qkv[rb + d];
  __syncthreads();
  float mx = -1e30f, l = 0.f;
  float acc[32];
#pragma unroll
  for (int d = 0; d < 32; ++d) acc[d] = 0.f;
  for (int j = 0; j < 64; ++j) {
    float s = 0.f;
#pragma unroll
    for (int d = 0; d < 32; ++d) s += q[d] * kls[j * 32 + d];
    s *= 0.17677669529663687f;  // 1/sqrt(32)
    float nm = fmaxf(mx, s);
    float co = __expf(mx - nm);
    float p = __expf(s - nm);
    l = l * co + p;
#pragma unroll
    for (int d = 0; d < 32; ++d) acc[d] = acc[d] * co + p * vls[j * 32 + d];
    mx = nm;
  }
  float inv = 1.f / l;
  float* op = ctx + ((size_t)(mol * 64 + lane)) * 256 + head * 32;
#pragma unroll
  for (int d = 0; d < 32; ++d) op[d] = acc[d] * inv;
}

// graph_vecs[mol][c] = sum over 64 atoms
__global__ __launch_bounds__(256) void gv_k(const float* __restrict__ af, float* __restrict__ gv) {
  int mol = blockIdx.x, c = threadIdx.x;
  float s = 0.f;
  for (int a = 0; a < 64; ++a) s += af[((size_t)mol * 64 + a) * HID + c];
  gv[mol * HID + c] = s;
}

// graph head: relu(gv@G1+g1)@G2+g2 -> out[mol*12289+12288]
__global__ __launch_bounds__(512) void gh_k(const float* __restrict__ gv, const float* __restrict__ G1,
                                            const float* __restrict__ g1, const float* __restrict__ G2,
                                            const float* __restrict__ g2, float* __restrict__ out) {
  __shared__ float xs[256];
  __shared__ float red[512];
  int mol = blockIdx.x, j = threadIdx.x;
  if (j < 256) xs[j] = gv[mol * 256 + j];
  __syncthreads();
  float s = 0.f;
  for (int k = 0; k < 256; ++k) s += xs[k] * G1[k * 512 + j];
  s = fmaxf(s + g1[j], 0.f);
  red[j] = s * G2[j];
  __syncthreads();
  for (int st = 256; st > 0; st >>= 1) {
    if (j < st) red[j] += red[j + st];
    __syncthreads();
  }
  if (j == 0) out[(size_t)mol * OUT_STRIDE + 12288] = red[0] + g2[0];
}

extern "C" void kernel_launch(void* const* d_in, const int* in_sizes, int n_in,
                              void* d_out, int out_size, void* d_ws, size_t ws_size,
                              hipStream_t stream) {
  (void)in_sizes; (void)n_in; (void)out_size; (void)ws_size;
  const float* f_atoms  = (const float*)d_in[0];
  const float* f_bonds  = (const float*)d_in[1];
  const float* prev_hid = (const float*)d_in[2];
  const float* W_i   = (const float*)d_in[7];
  const float* W_h   = (const float*)d_in[8];
  const float* W_o   = (const float*)d_in[9];
  const float* b_o   = (const float*)d_in[10];
  const float* Wq    = (const float*)d_in[11];
  const float* Wk    = (const float*)d_in[12];
  const float* Wv    = (const float*)d_in[13];
  const float* Wattn = (const float*)d_in[14];
  const float* W_vv  = (const float*)d_in[15];
  const float* W_vc  = (const float*)d_in[16];
  const float* A1    = (const float*)d_in[17];
  const float* a1    = (const float*)d_in[18];
  const float* A2    = (const float*)d_in[19];
  const float* a2    = (const float*)d_in[20];
  const float* B1    = (const float*)d_in[21];
  const float* b1    = (const float*)d_in[22];
  const float* B2    = (const float*)d_in[23];
  const float* b2b   = (const float*)d_in[24];
  const float* G1    = (const float*)d_in[25];
  const float* g1    = (const float*)d_in[26];
  const float* G2    = (const float*)d_in[27];
  const float* g2    = (const float*)d_in[28];
  float* out = (float*)d_out;

  // ---- fp32 workspace, 168.3 MB total (< known-good 187.3) ----
  char* base = (char*)d_ws;
  float* h     = (float*)(base);                    // [0, 134217728)  h fp32
  float* asumf = (float*)(base + 134217728);        // [134.2M, 167.8M)
  float* gvec  = (float*)(base + 167772160);        // 0.5 MB
  // post-loop aliases (sequential-stream lifetimes audited):
  float* xA    = (float*)(base);                    // 33.5 MB  a_feats (step 4-7)
  float* qkv   = (float*)(base + 33554432);         // 100.7 MB (step 5-6)
  float* ctx   = (float*)(base + 134217728);        // 33.5 MB  (step 6-7, over dead asumf)
  float* afat  = (float*)(base + 33554432);         // 33.5 MB  (step 7-8, over dead qkv)
  float* atomf = (float*)(base + 134217728);        // 33.5 MB  (step 8-end, over dead ctx)
  float* t1    = (float*)(base);                    // 67.1 MB  (step 9)
  float* t2    = (float*)(base);                    // 134.2 MB (step 10)

  // 1) h = h0 = relu(f_bonds @ W_i)
  fgemm<0><<<dim3(2048, 4), 256, 0, stream>>>(
      f_bonds, nullptr, W_i, nullptr, nullptr, nullptr, h,
      N_DIR, 256, 111, 111, 256, 256, 0, 1, 0);

  // 2) DMPNN loop, fully fp32, in-place h
  for (int d = 0; d < 9; ++d) {
    asum_f<<<8192, 256, 0, stream>>>(h, asumf);
    msg_f<<<1024, 1024, 0, stream>>>(asumf, h, W_h, W_i, f_bonds);
  }

  // 3) a_in
  asum_f<<<8192, 256, 0, stream>>>(h, asumf);
  // 4) a_feats = relu([f_atoms | a_in] @ W_o + b_o)
  fgemm<2><<<dim3(512, 4), 256, 0, stream>>>(
      asumf, f_atoms, W_o, nullptr, nullptr, b_o, xA,
      N_ATOMS, 256, 354, 0, 256, 256, 0, 1, 0);
  // 5) qkv
  fgemm<0><<<dim3(512, 4), 256, 0, stream>>>(
      xA, nullptr, Wq, nullptr, nullptr, nullptr, qkv,
      N_ATOMS, 256, 256, 256, 256, 768, 0, 0, 0);
  fgemm<0><<<dim3(512, 4), 256, 0, stream>>>(
      xA, nullptr, Wk, nullptr, nullptr, nullptr, qkv,
      N_ATOMS, 256, 256, 256, 256, 768, 256, 0, 0);
  fgemm<0><<<dim3(512, 4), 256, 0, stream>>>(
      xA, nullptr, Wv, nullptr, nullptr, nullptr, qkv,
      N_ATOMS, 256, 256, 256, 256, 768, 512, 0, 0);
  // 6) attention
  attn_k<<<4096, 64, 0, stream>>>(qkv, ctx);
  // 7) a_feats' = x + ctx @ Wattn
  fgemm<0><<<dim3(512, 4), 256, 0, stream>>>(
      ctx, nullptr, Wattn, nullptr, xA, nullptr, afat,
      N_ATOMS, 256, 256, 256, 256, 256, 0, 0, 0);
  // 8) atom_feats = relu(afat @ W_vc^T + prev_hid @ W_vv^T)
  fgemm<3><<<dim3(512, 4), 256, 0, stream>>>(
      afat, prev_hid, W_vc, W_vv, nullptr, nullptr, atomf,
      N_ATOMS, 256, 512, 0, 0, 256, 0, 1, 0);
  // 9) atom head
  fgemm<0><<<dim3(512, 8), 256, 0, stream>>>(
      atomf, nullptr, A1, nullptr, nullptr, a1, t1,
      N_ATOMS, 512, 256, 256, 512, 512, 0, 1, 0);
  fgemm<0><<<dim3(512, 2), 256, 0, stream>>>(
      t1, nullptr, A2, nullptr, nullptr, a2, out,
      N_ATOMS, 128, 512, 512, 128, 0, 0, 0, 2);
  // 10) bond head
  fgemm<4><<<dim3(1024, 8), 256, 0, stream>>>(
      atomf, nullptr, B1, nullptr, nullptr, b1, t2,
      N_UND, 512, 512, 0, 512, 512, 0, 1, 0);
  fgemm<0><<<dim3(1024, 1), 256, 0, stream>>>(
      t2, nullptr, B2, nullptr, nullptr, b2b, out,
      N_UND, 32, 512, 512, 32, 0, 0, 0, 3);
  // 11) graph head
  gv_k<<<512, 256, 0, stream>>>(atomf, gvec);
  gh_k<<<512, 512, 0, stream>>>(gvec, G1, g1, G2, g2, out);
}